// Round 7
// baseline (480.920 us; speedup 1.0000x reference)
//
#include <hip/hip_runtime.h>
#include <cstdint>
#include <cstddef>

using u16 = unsigned short;
using u32 = unsigned int;

#define DI __device__ __forceinline__

typedef __attribute__((ext_vector_type(8))) short bf16x8;
typedef __attribute__((ext_vector_type(4))) float f32x4;

// bf16 <-> f32 helpers (bit math). Intermediates stored bf16 in ws.
DI float bfu2f(u16 u) { return __uint_as_float(((u32)u) << 16); }
DI u16 f2bu(float f) {  // round-to-nearest-even, finite inputs only
    u32 x = __float_as_uint(f);
    return (u16)((x + 0x7fffu + ((x >> 16) & 1u)) >> 16);
}
DI u32 pk2(float a, float b) { return (u32)f2bu(a) | ((u32)f2bu(b) << 16); }

constexpr int CIN = 512;
constexpr int HW  = 4096;              // 64*64
constexpr size_t PLANE = 16777216ull;  // 8*512*4096 elements per output tensor

// ===== prep: x (b,512,4096) f32 -> XT (b,4096,512) bf16; + Wcat (fused) =====
// grid (64, 17, 8): y<16 -> XT tiles; y==16 -> Wcat[640][512] bf16 concat.
__global__ __launch_bounds__(256) void x_cl_bf16(
    const float* __restrict__ x2, const float* __restrict__ x1,
    const float* __restrict__ q_w, const float* __restrict__ k_w,
    const float* __restrict__ v_w,
    u16* __restrict__ XT2, u16* __restrict__ XT1, u16* __restrict__ Wcat)
{
    const int tid = threadIdx.x;
    if (blockIdx.y == 16) {                 // Wcat part: 160 useful blocks
        const int id = blockIdx.z * 64 + blockIdx.x;
        if (id >= 160) return;
        const int e0 = (id * 256 + tid) * 8;          // 640*512 elems
        const int row = e0 >> 9, col = e0 & 511;
        const float* src = (row < 64)  ? q_w + ((size_t)row << 9)
                         : (row < 128) ? k_w + ((size_t)(row - 64) << 9)
                                       : v_w + ((size_t)(row - 128) << 9);
        float4 f0 = *(const float4*)(src + col), f1 = *(const float4*)(src + col + 4);
        uint4 u = { pk2(f0.x, f0.y), pk2(f0.z, f0.w), pk2(f1.x, f1.y), pk2(f1.z, f1.w) };
        *(uint4*)(Wcat + e0) = u;
        return;
    }
    __shared__ u16 t[64][72];
    const int st = blockIdx.x;
    const int ct = blockIdx.y & 7, sel = blockIdx.y >> 3;
    const int b  = blockIdx.z;
    const float* x = sel ? x1 : x2;
    u16* XT = sel ? XT1 : XT2;
    const int c0 = ct * 64, s0 = st * 64;
    {
        const int c = tid >> 2, q = (tid & 3) * 16;
        const float* p = x + ((size_t)b * 512 + c0 + c) * 4096 + s0 + q;
        float4 f0 = *(const float4*)p,       f1 = *(const float4*)(p + 4);
        float4 f2 = *(const float4*)(p + 8), f3 = *(const float4*)(p + 12);
        uint4 u0 = { pk2(f0.x, f0.y), pk2(f0.z, f0.w), pk2(f1.x, f1.y), pk2(f1.z, f1.w) };
        uint4 u1 = { pk2(f2.x, f2.y), pk2(f2.z, f2.w), pk2(f3.x, f3.y), pk2(f3.z, f3.w) };
        *(uint4*)&t[c][q]     = u0;
        *(uint4*)&t[c][q + 8] = u1;
    }
    __syncthreads();
    {
        const int s = tid >> 2, q = (tid & 3) * 16;
        u16 tmp[16];
        #pragma unroll
        for (int i = 0; i < 16; i++) tmp[i] = t[q + i][s];
        u16* dp = XT + ((size_t)b * 4096 + s0 + s) * 512 + c0 + q;
        *(uint4*)&dp[0] = *(uint4*)&tmp[0];
        *(uint4*)&dp[8] = *(uint4*)&tmp[8];
    }
}

// ================= MFMA projection GEMM (bf16 operands, BK=64) ==============
// Rows m: [0,64)=q->qc, [64,128)=k->kc (channel-last direct), [128,640)=v2,
// [640,1152)=v1 (Wcat rows 128-639 reused).  D[n][m]: A = XT rows, B = Wcat.
// grid (256 n-tiles, 9 m-tiles), block 256 (4 waves).
__global__ __launch_bounds__(256) void proj_mfma(
    const u16* __restrict__ XT2, const u16* __restrict__ XT1,
    const u16* __restrict__ Wcat,
    const float* __restrict__ q_b, const float* __restrict__ k_b,
    const float* __restrict__ v_b,
    u16* __restrict__ oqc, u16* __restrict__ okc,
    u16* __restrict__ ov2, u16* __restrict__ ov1)
{
    __shared__ u16 Xl[128][72];   // [n][k], rows 144 B
    __shared__ u16 Wl[128][72];   // [m][k]
    const int tid = threadIdx.x;
    const int m0  = blockIdx.y * 128;          // 0..1151
    const int n0g = blockIdx.x * 128;
    const int b    = n0g >> 12;
    const int col0 = n0g & 4095;
    const u16* Xb = ((m0 < 640) ? XT2 : XT1) + ((size_t)b * 4096 + col0) * 512;
    const u16* Wb = Wcat + (size_t)((m0 < 640) ? m0 : m0 - 512) * 512;

    const int srow = tid >> 1, soff = (tid & 1) * 32;  // 2 thr/row, 64 B each
    const u16* xp = Xb + (size_t)srow * 512 + soff;
    const u16* wp = Wb + (size_t)srow * 512 + soff;

    const int lane = tid & 63, wv = tid >> 6;
    const int wn = (wv & 1) * 64;   // n-offset (D rows)
    const int wm = (wv >> 1) * 64;  // m-offset (D cols)
    const int lr = lane & 15, lq = lane >> 4;

    f32x4 acc[4][4] = {};           // [i: n-frag][j: m-frag]
    for (int kt = 0; kt < CIN; kt += 64) {
        #pragma unroll
        for (int t = 0; t < 4; t++) {
            *(uint4*)&Xl[srow][soff + 8 * t] = *(const uint4*)(xp + kt + 8 * t);
            *(uint4*)&Wl[srow][soff + 8 * t] = *(const uint4*)(wp + kt + 8 * t);
        }
        __syncthreads();
        #pragma unroll
        for (int ks = 0; ks < 2; ks++) {
            const int k0 = ks * 32 + lq * 8;
            bf16x8 a[4], bb[4];
            #pragma unroll
            for (int i = 0; i < 4; i++)
                a[i] = *(const bf16x8*)&Xl[wn + i * 16 + lr][k0];
            #pragma unroll
            for (int j = 0; j < 4; j++)
                bb[j] = *(const bf16x8*)&Wl[wm + j * 16 + lr][k0];
            #pragma unroll
            for (int j = 0; j < 4; j++)
                #pragma unroll
                for (int i = 0; i < 4; i++)
                    acc[i][j] = __builtin_amdgcn_mfma_f32_16x16x32_bf16(a[i], bb[j], acc[i][j], 0, 0, 0);
        }
        __syncthreads();
    }
    // epilogue: D row = n (lq*4+r consecutive), col = m (lr).
    if (m0 == 0) {
        // q/k -> channel-last qc/kc[(b,s,64c)]: lanes span c -> 32B groups.
        #pragma unroll
        for (int j = 0; j < 4; j++) {
            const int mbase = wm + j * 16;             // 0..127
            const float* bp = (mbase < 64) ? q_b : k_b;
            u16* op = (mbase < 64) ? oqc : okc;
            const int ch = (mbase & 63) + lr;
            const float bias = bp[ch];
            #pragma unroll
            for (int i = 0; i < 4; i++) {
                const int s = col0 + wn + i * 16 + lq * 4;
                u16* ob = op + ((size_t)b * 4096 + s) * 64 + ch;
                #pragma unroll
                for (int r = 0; r < 4; r++)
                    ob[(size_t)r * 64] = f2bu(acc[i][j][r] + bias);
            }
        }
    } else {
        #pragma unroll
        for (int j = 0; j < 4; j++) {
            const int mbase = m0 + wm + j * 16;        // 128..1151
            u16* op; int ch0;
            if (mbase < 640) { op = ov2; ch0 = mbase - 128; }
            else             { op = ov1; ch0 = mbase - 640; }
            const int ch = ch0 + lr;
            const float bias = v_b[ch];
            u16* obase = op + ((size_t)b * 512 + ch) * HW + col0 + wn + lq * 4;
            #pragma unroll
            for (int i = 0; i < 4; i++) {
                uint2 pkd = { pk2(acc[i][j][0] + bias, acc[i][j][1] + bias),
                              pk2(acc[i][j][2] + bias, acc[i][j][3] + bias) };
                *(uint2*)(obase + i * 16) = pkd;
            }
        }
    }
}

// ============== 64x64 last-two-dims transpose (bf16), vectorized ==========
__global__ __launch_bounds__(256) void transpose64_bb(
    const u16* __restrict__ src, u16* __restrict__ dst)
{
    __shared__ u16 t[64][72];
    const size_t s = blockIdx.x;
    const u16* sp = src + s * 4096;
    u16* dp = dst + s * 4096;
    const int tid = threadIdx.x;
    const int r = tid >> 2, q = (tid & 3) * 16;
    {
        uint4 a0 = *(const uint4*)(sp + r * 64 + q);
        uint4 a1 = *(const uint4*)(sp + r * 64 + q + 8);
        *(uint4*)&t[r][q]     = a0;
        *(uint4*)&t[r][q + 8] = a1;
    }
    __syncthreads();
    {
        u16 tmp[16];
        #pragma unroll
        for (int i = 0; i < 16; i++) tmp[i] = t[q + i][r];
        *(uint4*)&dp[r * 64 + q]     = *(uint4*)&tmp[0];
        *(uint4*)&dp[r * 64 + q + 8] = *(uint4*)&tmp[8];
    }
}

// ============== in-place per-slice 64x64 bf16 transpose, vectorized =======
__global__ __launch_bounds__(256) void transpose64_bb_inplace(u16* __restrict__ d)
{
    __shared__ u16 t[64][72];
    u16* p = d + (size_t)blockIdx.x * 4096;
    const int tid = threadIdx.x;
    const int r = tid >> 2, q = (tid & 3) * 16;
    {
        uint4 a0 = *(const uint4*)(p + r * 64 + q);
        uint4 a1 = *(const uint4*)(p + r * 64 + q + 8);
        *(uint4*)&t[r][q]     = a0;
        *(uint4*)&t[r][q + 8] = a1;
    }
    __syncthreads();
    {
        u16 tmp[16];
        #pragma unroll
        for (int i = 0; i < 16; i++) tmp[i] = t[q + i][r];
        *(uint4*)&p[r * 64 + q]     = *(uint4*)&tmp[0];
        *(uint4*)&p[r * 64 + q + 8] = *(uint4*)&tmp[8];
    }
}

// ======================= energies (MFMA) =======================
// e layout: (b,h,w,128) fp32. [0:64) = energy_H, [64:128) = energy_W.
// qc/kc: channel-last (b, h*64+w, 64c) bf16.
__global__ __launch_bounds__(256) void energy_h_mfma(
    const u16* __restrict__ qc, const u16* __restrict__ kc, float* __restrict__ e)
{
    __shared__ u16 Qs[64][72], Ks[64][72];  // [h][c] rows 144B
    const int w = blockIdx.x, b = blockIdx.y;
    const int tid = threadIdx.x;
    {
        const int row = tid >> 2, ch = (tid & 3) * 16;
        const size_t g = ((size_t)b * 4096 + (size_t)row * 64 + w) * 64 + ch;
        *(uint4*)&Qs[row][ch]     = *(const uint4*)(qc + g);
        *(uint4*)&Qs[row][ch + 8] = *(const uint4*)(qc + g + 8);
        *(uint4*)&Ks[row][ch]     = *(const uint4*)(kc + g);
        *(uint4*)&Ks[row][ch + 8] = *(const uint4*)(kc + g + 8);
    }
    __syncthreads();
    const int lane = tid & 63, wv = tid >> 6;
    const int mH = (wv & 1) * 32, nh = (wv >> 1) * 32;
    const int lr = lane & 15, lq = lane >> 4;
    f32x4 acc[2][2] = {};
    #pragma unroll
    for (int kt = 0; kt < 2; kt++) {
        const int k0 = kt * 32 + lq * 8;
        bf16x8 afr[2], bfr[2];
        #pragma unroll
        for (int i = 0; i < 2; i++) afr[i] = *(const bf16x8*)&Ks[mH + i * 16 + lr][k0];
        #pragma unroll
        for (int j = 0; j < 2; j++) bfr[j] = *(const bf16x8*)&Qs[nh + j * 16 + lr][k0];
        #pragma unroll
        for (int j = 0; j < 2; j++)
            #pragma unroll
            for (int i = 0; i < 2; i++)
                acc[i][j] = __builtin_amdgcn_mfma_f32_16x16x32_bf16(afr[i], bfr[j], acc[i][j], 0, 0, 0);
    }
    #pragma unroll
    for (int i = 0; i < 2; i++)
        #pragma unroll
        for (int j = 0; j < 2; j++) {
            const int h = nh + j * 16 + lr;
            const int Hp = mH + i * 16 + lq * 4;
            float4 v = make_float4(acc[i][j][0], acc[i][j][1], acc[i][j][2], acc[i][j][3]);
            *reinterpret_cast<float4*>(e + ((size_t)(b * 64 + h) * 64 + w) * 128 + Hp) = v;
        }
}

__global__ __launch_bounds__(256) void energy_w_mfma(
    const u16* __restrict__ qc, const u16* __restrict__ kc, float* __restrict__ e)
{
    __shared__ u16 Qs[64][72], Ks[64][72];  // [w][c]
    const int h = blockIdx.x, b = blockIdx.y;
    const int tid = threadIdx.x;
    {
        const int row = tid >> 2, ch = (tid & 3) * 16;
        const size_t g = ((size_t)b * 4096 + (size_t)h * 64 + row) * 64 + ch;
        *(uint4*)&Qs[row][ch]     = *(const uint4*)(qc + g);
        *(uint4*)&Qs[row][ch + 8] = *(const uint4*)(qc + g + 8);
        *(uint4*)&Ks[row][ch]     = *(const uint4*)(kc + g);
        *(uint4*)&Ks[row][ch + 8] = *(const uint4*)(kc + g + 8);
    }
    __syncthreads();
    const int lane = tid & 63, wv = tid >> 6;
    const int mW = (wv & 1) * 32, nw = (wv >> 1) * 32;
    const int lr = lane & 15, lq = lane >> 4;
    f32x4 acc[2][2] = {};
    #pragma unroll
    for (int kt = 0; kt < 2; kt++) {
        const int k0 = kt * 32 + lq * 8;
        bf16x8 afr[2], bfr[2];
        #pragma unroll
        for (int i = 0; i < 2; i++) afr[i] = *(const bf16x8*)&Ks[mW + i * 16 + lr][k0];
        #pragma unroll
        for (int j = 0; j < 2; j++) bfr[j] = *(const bf16x8*)&Qs[nw + j * 16 + lr][k0];
        #pragma unroll
        for (int j = 0; j < 2; j++)
            #pragma unroll
            for (int i = 0; i < 2; i++)
                acc[i][j] = __builtin_amdgcn_mfma_f32_16x16x32_bf16(afr[i], bfr[j], acc[i][j], 0, 0, 0);
    }
    #pragma unroll
    for (int i = 0; i < 2; i++)
        #pragma unroll
        for (int j = 0; j < 2; j++) {
            const int w = nw + j * 16 + lr;
            const int Wp = mW + i * 16 + lq * 4;
            float4 v = make_float4(acc[i][j][0], acc[i][j][1], acc[i][j][2], acc[i][j][3]);
            *reinterpret_cast<float4*>(e + ((size_t)(b * 64 + h) * 64 + w) * 128 + 64 + Wp) = v;
        }
}

// ============ softmax over 128, f32 in -> bf16 out ============
__global__ __launch_bounds__(256) void softmax128_bf(
    const float* __restrict__ e, u16* __restrict__ attb)
{
    const int pos = blockIdx.x * 4 + (threadIdx.x >> 6);
    const int l = threadIdx.x & 63;
    const float* p = e + (size_t)pos * 128;
    float v0 = p[l], v1 = p[l + 64];
    float m = fmaxf(v0, v1);
    #pragma unroll
    for (int o = 32; o > 0; o >>= 1) m = fmaxf(m, __shfl_xor(m, o, 64));
    float e0 = __expf(v0 - m), e1 = __expf(v1 - m);
    float s = e0 + e1;
    #pragma unroll
    for (int o = 32; o > 0; o >>= 1) s += __shfl_xor(s, o, 64);
    float inv = 1.0f / s;
    u16* q = attb + (size_t)pos * 128;
    q[l] = f2bu(e0 * inv);
    q[l + 64] = f2bu(e1 * inv);
}

// ======================= H-aggregation (MFMA, LDS-staged, in-place) =======
// P[b,c,w,h] = sum_H' vT[b,c,w,H'] * attH[b,h,w,H']  (c-tile 128, D row = c,
// col = h; bf16 out over the vT rows the block itself read).
// grid (mt=8, w=64, b=8). mt 0-3 -> a-side, 4-7 -> b-side.
__global__ __launch_bounds__(256) void agg_h_mfma(
    const u16* __restrict__ vTa, const u16* __restrict__ vTb,
    const u16* __restrict__ attb, u16* __restrict__ Pa, u16* __restrict__ Pb)
{
    __shared__ u16 Vs[128][72];  // [c][H'], rows 144 B
    __shared__ u16 As[64][72];   // [h][H']
    const int mt = blockIdx.x, w = blockIdx.y, b = blockIdx.z;
    const u16* vT = (mt < 4) ? vTa : vTb;
    u16*       P  = (mt < 4) ? Pa  : Pb;
    const int c0 = (mt & 3) * 128;
    const int tid = threadIdx.x;
    const u16* va = vT + ((size_t)(b * 512 + c0) * 64 + w) * 64;          // + c*4096 + H'
    const u16* ab = attb + ((size_t)b * 4096 + w) * 128;                  // + h*8192 + H'
    {
        const int r = tid >> 3, cB = (tid & 7) * 8;
        #pragma unroll
        for (int i = 0; i < 4; i++)
            *(uint4*)&Vs[r + 32 * i][cB] = *(const uint4*)(va + (size_t)(r + 32 * i) * 4096 + cB);
        #pragma unroll
        for (int i = 0; i < 2; i++)
            *(uint4*)&As[r + 32 * i][cB] = *(const uint4*)(ab + (size_t)(r + 32 * i) * 8192 + cB);
    }
    __syncthreads();
    const int lane = tid & 63, wv = tid >> 6;
    const int wm = (wv & 1) * 64, wn = (wv >> 1) * 32;
    const int lr = lane & 15, lq = lane >> 4;
    f32x4 acc[4][2] = {};
    #pragma unroll
    for (int kt = 0; kt < 2; kt++) {
        const int k0 = kt * 32 + lq * 8;
        bf16x8 afr[4], bfr[2];
        #pragma unroll
        for (int i = 0; i < 4; i++) afr[i] = *(const bf16x8*)&Vs[wm + i * 16 + lr][k0];
        #pragma unroll
        for (int j = 0; j < 2; j++) bfr[j] = *(const bf16x8*)&As[wn + j * 16 + lr][k0];
        #pragma unroll
        for (int j = 0; j < 2; j++)
            #pragma unroll
            for (int i = 0; i < 4; i++)
                acc[i][j] = __builtin_amdgcn_mfma_f32_16x16x32_bf16(afr[i], bfr[j], acc[i][j], 0, 0, 0);
    }
    // D: row(c within 16-tile) = lq*4+r, col(h) = lr
    #pragma unroll
    for (int i = 0; i < 4; i++)
        #pragma unroll
        for (int j = 0; j < 2; j++) {
            u16* pp = P + ((size_t)(b * 512 + c0 + wm + i * 16 + lq * 4) * 64 + w) * 64 + wn + j * 16 + lr;
            #pragma unroll
            for (int r = 0; r < 4; r++) pp[(size_t)r * 4096] = f2bu(acc[i][j][r]);
        }
}

// ======================= W-aggregation (MFMA, LDS-staged) + epilogue ======
// c-tile 128, D row = c, col = w.  y = g*(P + OutW) + x.
// Epilogue batched: per i-frag, issue all 8 P + 8 x loads, then FMA+store.
__global__ __launch_bounds__(256) void agg_w_mfma(
    const u16* __restrict__ v2, const u16* __restrict__ v1,
    const u16* __restrict__ P2, const u16* __restrict__ P1,
    const u16* __restrict__ attb,
    const float* __restrict__ x2, const float* __restrict__ x1,
    const float* __restrict__ gptr, float* __restrict__ out)
{
    __shared__ u16 Vs[128][72];  // [c][W']
    __shared__ u16 As[64][72];   // [w][W']
    const int mt = blockIdx.x, h = blockIdx.y, b = blockIdx.z;
    const u16* v = (mt < 4) ? v2 : v1;
    const u16* P = (mt < 4) ? P2 : P1;
    const float* x = (mt < 4) ? x2 : x1;
    float* y = out + ((mt < 4) ? 0 : PLANE);
    const int c0 = (mt & 3) * 128;
    const int tid = threadIdx.x;
    const u16* vb = v + (size_t)(b * 512 + c0) * 4096 + h * 64;           // + c*4096 + W'
    const u16* ab = attb + ((size_t)(b * 64 + h) * 64) * 128 + 64;        // + w*128 + W'
    {
        const int r = tid >> 3, cB = (tid & 7) * 8;
        #pragma unroll
        for (int i = 0; i < 4; i++)
            *(uint4*)&Vs[r + 32 * i][cB] = *(const uint4*)(vb + (size_t)(r + 32 * i) * 4096 + cB);
        #pragma unroll
        for (int i = 0; i < 2; i++)
            *(uint4*)&As[r + 32 * i][cB] = *(const uint4*)(ab + (size_t)(r + 32 * i) * 128 + cB);
    }
    __syncthreads();
    const int lane = tid & 63, wv = tid >> 6;
    const int wm = (wv & 1) * 64, wn = (wv >> 1) * 32;
    const int lr = lane & 15, lq = lane >> 4;
    f32x4 acc[4][2] = {};
    #pragma unroll
    for (int kt = 0; kt < 2; kt++) {
        const int k0 = kt * 32 + lq * 8;
        bf16x8 afr[4], bfr[2];
        #pragma unroll
        for (int i = 0; i < 4; i++) afr[i] = *(const bf16x8*)&Vs[wm + i * 16 + lr][k0];
        #pragma unroll
        for (int j = 0; j < 2; j++) bfr[j] = *(const bf16x8*)&As[wn + j * 16 + lr][k0];
        #pragma unroll
        for (int j = 0; j < 2; j++)
            #pragma unroll
            for (int i = 0; i < 4; i++)
                acc[i][j] = __builtin_amdgcn_mfma_f32_16x16x32_bf16(afr[i], bfr[j], acc[i][j], 0, 0, 0);
    }
    const float g = gptr[0];
    #pragma unroll
    for (int i = 0; i < 4; i++) {
        const size_t off0 = (size_t)(b * 512 + c0 + wm + i * 16 + lq * 4) * 4096
                          + (size_t)h * 64 + wn + lr;
        u16 pr[8]; float xr[8];
        #pragma unroll
        for (int j = 0; j < 2; j++)
            #pragma unroll
            for (int r = 0; r < 4; r++) {
                const size_t o = off0 + j * 16 + (size_t)r * 4096;
                pr[j * 4 + r] = P[o];
                xr[j * 4 + r] = x[o];
            }
        #pragma unroll
        for (int j = 0; j < 2; j++)
            #pragma unroll
            for (int r = 0; r < 4; r++) {
                const size_t o = off0 + j * 16 + (size_t)r * 4096;
                y[o] = g * (bfu2f(pr[j * 4 + r]) + acc[i][j][r]) + xr[j * 4 + r];
            }
    }
}

// ======================= host =======================
extern "C" void kernel_launch(void* const* d_in, const int* in_sizes, int n_in,
                              void* d_out, int out_size, void* d_ws, size_t ws_size,
                              hipStream_t stream)
{
    (void)in_sizes; (void)n_in; (void)out_size; (void)ws_size;
    const float* x2  = (const float*)d_in[0];
    const float* x1  = (const float*)d_in[1];
    const float* q_w = (const float*)d_in[2];
    const float* q_b = (const float*)d_in[3];
    const float* k_w = (const float*)d_in[4];
    const float* k_b = (const float*)d_in[5];
    const float* v_w = (const float*)d_in[6];
    const float* v_b = (const float*)d_in[7];
    const float* gm  = (const float*)d_in[8];

    // ws (MiB), time-disjoint overlays:
    //   v2 0-32 | v1 32-64
    //   XT2 64-96 | XT1 96-128 | Wcat 128-130   (prep; dead after proj)
    //   qc 136-140 | kc 140-144                 (proj out; dead after energies)
    //   e 88-104                                (energies out; dead after softmax)
    //   attb 64-72                              (softmax out)
    //   vT2/P2 72-104 | vT1/P1 104-136          (after softmax)
    // Max 144 MiB.
    char* ws = (char*)d_ws;
    u16*   v2   = (u16*)(ws);
    u16*   v1   = (u16*)(ws + ((size_t)32  << 20));
    u16*   attb = (u16*)(ws + ((size_t)64  << 20));
    u16*   XT2  = (u16*)(ws + ((size_t)64  << 20));
    u16*   XT1  = (u16*)(ws + ((size_t)96  << 20));
    u16*   Wcat = (u16*)(ws + ((size_t)128 << 20));
    float* e    = (float*)(ws + ((size_t)88 << 20));
    u16*   vT2  = (u16*)(ws + ((size_t)72  << 20));
    u16*   vT1  = (u16*)(ws + ((size_t)104 << 20));
    u16*   qc   = (u16*)(ws + ((size_t)136 << 20));
    u16*   kc   = (u16*)(ws + ((size_t)140 << 20));
    float* out = (float*)d_out;

    dim3 blk(256);
    x_cl_bf16<<<dim3(64, 17, 8), blk, 0, stream>>>(x2, x1, q_w, k_w, v_w,
                                                   XT2, XT1, Wcat);
    proj_mfma<<<dim3(256, 9), blk, 0, stream>>>(XT2, XT1, Wcat, q_b, k_b, v_b,
                                                qc, kc, v2, v1);
    energy_h_mfma<<<dim3(64, 8), blk, 0, stream>>>(qc, kc, e);
    energy_w_mfma<<<dim3(64, 8), blk, 0, stream>>>(qc, kc, e);
    softmax128_bf<<<8192, blk, 0, stream>>>(e, attb);       // e dead after this
    transpose64_bb<<<8192, blk, 0, stream>>>(v2, vT2);      // v2+v1 -> vT2+vT1
    agg_h_mfma<<<dim3(8, 64, 8), blk, 0, stream>>>(vT2, vT1, attb, vT2, vT1); // P over vT
    transpose64_bb_inplace<<<8192, blk, 0, stream>>>(vT2);  // P -> (b,c,h,w)
    agg_w_mfma<<<dim3(8, 64, 8), blk, 0, stream>>>(v2, v1, vT2, vT1, attb,
                                                   x2, x1, gm, out);
}